// Round 15
// baseline (414.646 us; speedup 1.0000x reference)
//
#include <hip/hip_runtime.h>

// Problem constants: B=32, S=4096, H=512, E=512
typedef __attribute__((ext_vector_type(8))) short bf16x8;
typedef __attribute__((ext_vector_type(4))) float f32x4;

__device__ inline unsigned int cvt_pk_bf16(float lo, float hi){
  unsigned int r;
  asm("v_cvt_pk_bf16_f32 %0, %1, %2" : "=v"(r) : "v"(lo), "v"(hi));
  return r;
}
__device__ inline float fast_tanh(float x){
  float e = __builtin_amdgcn_exp2f(x * 2.8853900817779268f);
  return 1.0f - 2.0f * __builtin_amdgcn_rcpf(e + 1.0f);
}
#define LOG2E 1.4426950408889634f

// ---- K0: We [512][512] f32 -> bf16, laid out as 32 chunk images of [16][512]
// with XOR swizzle (byte ^= (row&7)<<4)  [round-2 verbatim]
__global__ __launch_bounds__(256) void we_conv(const float* __restrict__ We,
                                               unsigned int* __restrict__ weSwz){
  int gid = blockIdx.x * 256 + threadIdx.x;   // 32768 threads
  int n  = gid >> 6;        // row 0..511  (k-output index)
  int k8 = gid & 63;        // 8-element group along h
  const float4* src = (const float4*)(We + n*512 + k8*8);
  float4 f0 = src[0], f1 = src[1];
  unsigned int p0 = cvt_pk_bf16(f0.x, f0.y);
  unsigned int p1 = cvt_pk_bf16(f0.z, f0.w);
  unsigned int p2 = cvt_pk_bf16(f1.x, f1.y);
  unsigned int p3 = cvt_pk_bf16(f1.z, f1.w);
  int nc = n >> 4, r = n & 15;
  int byte = (k8*16) ^ ((r & 7) << 4);
  *(uint4*)((char*)weSwz + nc*16384 + r*1024 + byte) = make_uint4(p0,p1,p2,p3);
}

// ---- K1: gd[b][k] = h[b,:]·Wd[k,:] + bd[k] + be[k]
__global__ __launch_bounds__(256) void gd_kernel(const float* __restrict__ hvec,
                                                 const float* __restrict__ Wd,
                                                 const float* __restrict__ bd,
                                                 const float* __restrict__ be,
                                                 float* __restrict__ gd){
  __shared__ float hs[512];
  int b = blockIdx.x >> 2, kc = blockIdx.x & 3;
  int tid = threadIdx.x;
  hs[tid]       = hvec[b*512 + tid];
  hs[tid + 256] = hvec[b*512 + 256 + tid];
  __syncthreads();
  int k  = kc*128 + (tid >> 1);
  int hh = (tid & 1) * 256;
  const float4* wrow = (const float4*)(Wd + (size_t)k*512 + hh);
  const float4* hv4  = (const float4*)(hs + hh);
  float acc = 0.f;
  #pragma unroll 8
  for (int i = 0; i < 64; ++i){
    float4 w = wrow[i]; float4 u = hv4[i];
    acc += w.x*u.x + w.y*u.y + w.z*u.z + w.w*u.w;
  }
  acc += __shfl_xor(acc, 1);
  if ((tid & 1) == 0) gd[b*512 + k] = acc + bd[k] + be[k];
}

// ---- K2: round-2's measured-best score kernel (154us) + flash-ct epilogue.
// Block = 256 thr (4 waves), M-tile = 64 rows, 2048 blocks. A staged to LDS
// bf16 (swizzled) + register A-frags; We chunks [16][512] global->reg->LDS
// (T14); 16x16x32 MFMA; tanh+reduce in regs. Epilogue: block softmax
// partials + unnormalized ctp from the STILL-RESIDENT ldsA.
__global__ __launch_bounds__(256,2) void score_kernel(
    const float* __restrict__ ctx, const uint4* __restrict__ weSwz,
    const float* __restrict__ gd, const float* __restrict__ Wv,
    float* __restrict__ scores, unsigned int* __restrict__ ctp,
    float* __restrict__ MS){
  __shared__ uint4 ldsbuf[5120];               // 80 KiB -> 2 blocks/CU
  char* ldsA = (char*)ldsbuf;                  // 64 KiB: [64 rows][1024 B] swizzled
  char* ldsB = (char*)ldsbuf + 65536;          // 16 KiB: one We chunk image

  const int tid  = threadIdx.x;
  const int bid  = blockIdx.x;                 // 2048
  const int row0 = bid * 64;                   // global row = b*4096 + s
  const int b    = row0 >> 12;

  // prefetch We chunk 0
  uint4 bpre[4];
  #pragma unroll
  for (int i = 0; i < 4; ++i) bpre[i] = weSwz[i*256 + tid];

  { // stage A tile: 64 rows x 512 h, f32 -> bf16, swizzled
    const int r = tid >> 2, q = tid & 3;
    const float4* src = (const float4*)(ctx + ((long)(row0 + r) << 9)) + q*32;
    char* rowBase = ldsA + r*1024;
    const int swz = (r & 7) << 4;
    #pragma unroll
    for (int i = 0; i < 16; ++i){
      float4 f0 = src[i*2], f1 = src[i*2+1];
      unsigned int p0 = cvt_pk_bf16(f0.x, f0.y);
      unsigned int p1 = cvt_pk_bf16(f0.z, f0.w);
      unsigned int p2 = cvt_pk_bf16(f1.x, f1.y);
      unsigned int p3 = cvt_pk_bf16(f1.z, f1.w);
      int byteInRow = ((q*128 + i*8) * 2) ^ swz;
      *(uint4*)(rowBase + byteInRow) = make_uint4(p0,p1,p2,p3);
    }
  }
  __syncthreads();

  const int wid  = tid >> 6;
  const int lane = tid & 63;
  const int lrow = lane & 15;    // A row within wave tile / B col (k-out)
  const int kgrp = lane >> 4;    // k-group 0..3

  // A-fragments: 16 K-steps, register-resident for whole block (64 VGPR)
  bf16x8 afrag[16];
  {
    const int arow = wid*16 + lrow;
    const char* aBase = ldsA + arow*1024;
    const int aswz = (arow & 7) << 4;
    #pragma unroll
    for (int t = 0; t < 16; ++t){
      int byte = ((t*32 + kgrp*8)*2) ^ aswz;
      afrag[t] = *(const bf16x8*)(aBase + byte);
    }
  }
  #pragma unroll
  for (int i = 0; i < 4; ++i) *(uint4*)(ldsB + (i*256 + tid)*16) = bpre[i];
  __syncthreads();

  float sc0=0.f, sc1=0.f, sc2=0.f, sc3=0.f;
  const char* bBase = ldsB + lrow*1024;
  const int bswz = (lrow & 7) << 4;

  for (int nc = 0; nc < 32; ++nc){
    if (nc < 31){                       // T14: issue next-chunk loads early
      #pragma unroll
      for (int i = 0; i < 4; ++i) bpre[i] = weSwz[(nc+1)*1024 + i*256 + tid];
    }
    int colk = nc*16 + lrow;            // global k-output index
    float gdv = gd[b*512 + colk];
    float wvv = Wv[colk];
    f32x4 acc = {0.f,0.f,0.f,0.f};
    #pragma unroll
    for (int t = 0; t < 16; ++t){
      int byte = ((t*32 + kgrp*8)*2) ^ bswz;
      bf16x8 bfrag = *(const bf16x8*)(bBase + byte);
      acc = __builtin_amdgcn_mfma_f32_16x16x32_bf16(afrag[t], bfrag, acc, 0, 0, 0);
    }
    // D element (m,n): m = kgrp*4 + j (row), n = lrow (col) [m89 layout]
    sc0 += fast_tanh(acc[0] + gdv) * wvv;
    sc1 += fast_tanh(acc[1] + gdv) * wvv;
    sc2 += fast_tanh(acc[2] + gdv) * wvv;
    sc3 += fast_tanh(acc[3] + gdv) * wvv;
    __syncthreads();                    // everyone done reading ldsB
    if (nc < 31){
      #pragma unroll
      for (int i = 0; i < 4; ++i) *(uint4*)(ldsB + (i*256 + tid)*16) = bpre[i];
    }
    __syncthreads();                    // chunk nc+1 staged
  }

  // reduce over the 16 n-columns (lanes sharing kgrp are contiguous 16)
  #pragma unroll
  for (int m = 1; m < 16; m <<= 1){
    sc0 += __shfl_xor(sc0, m);
    sc1 += __shfl_xor(sc1, m);
    sc2 += __shfl_xor(sc2, m);
    sc3 += __shfl_xor(sc3, m);
  }

  // ---- epilogue: reuse ldsB region (main loop done) for scratch
  float* scl = (float*)ldsB;            // [64] block scores
  float* wl  = (float*)(ldsB + 256);    // [64] exp weights
  float* red = (float*)(ldsB + 512);    // [2]  {M, S}
  __syncthreads();                      // all waves done with ldsB reads

  if (lrow == 0){
    int rloc = wid*16 + kgrp*4;
    float* so = scores + row0 + rloc;
    so[0] = sc0; so[1] = sc1; so[2] = sc2; so[3] = sc3;
    scl[rloc] = sc0; scl[rloc+1] = sc1; scl[rloc+2] = sc2; scl[rloc+3] = sc3;
  }
  __syncthreads();

  if (tid < 64){
    float s = scl[tid];
    float M = s;
    #pragma unroll
    for (int o = 1; o < 64; o <<= 1) M = fmaxf(M, __shfl_xor(M, o));
    float w = __builtin_amdgcn_exp2f((s - M) * LOG2E);
    wl[tid] = w;
    float d = w;
    #pragma unroll
    for (int o = 1; o < 64; o <<= 1) d += __shfl_xor(d, o);
    if (tid == 0){ red[0] = M; red[1] = d; }
  }
  __syncthreads();

  // ctp[h] = sum_r wl[r] * A[r,h]; A still resident in ldsA (bf16 swizzled).
  // Thread owns h = 2*tid, 2*tid+1 (one u32 per row).
  float cA = 0.f, cB = 0.f;
  #pragma unroll 8
  for (int r = 0; r < 64; ++r){
    unsigned int u = *(const unsigned int*)(ldsA + r*1024 + ((tid*4) ^ ((r & 7) << 4)));
    float w = wl[r];
    union { unsigned int q; float f; } flo, fhi;
    flo.q = u << 16;
    fhi.q = u & 0xffff0000u;
    cA += w * flo.f;
    cB += w * fhi.f;
  }
  ctp[(size_t)bid*256 + tid] = cvt_pk_bf16(cA, cB);
  if (tid == 0){ MS[2*bid] = red[0]; MS[2*bid + 1] = red[1]; }
}

// ---- K3: combine 64 slab-partials per batch -> ct[b][512], mbuf[b]={M,1/den}
__global__ __launch_bounds__(256) void combine_kernel(const unsigned int* __restrict__ ctp,
                                                      const float* __restrict__ MS,
                                                      float* __restrict__ ct,
                                                      float* __restrict__ mbuf){
  __shared__ float wsh[64];
  __shared__ float msh[2];
  int b = blockIdx.x, tid = threadIdx.x;
  if (tid < 64){
    float Mi = MS[(b*64 + tid)*2];
    float Si = MS[(b*64 + tid)*2 + 1];
    float M = Mi;
    #pragma unroll
    for (int o = 1; o < 64; o <<= 1) M = fmaxf(M, __shfl_xor(M, o));
    float w = __builtin_amdgcn_exp2f((Mi - M) * LOG2E);
    float d = w * Si;
    #pragma unroll
    for (int o = 1; o < 64; o <<= 1) d += __shfl_xor(d, o);
    wsh[tid] = w;
    if (tid == 0){ msh[0] = M; msh[1] = 1.0f / d; }
  }
  __syncthreads();
  float invd = msh[1];
  float a0 = 0.f, a1 = 0.f;
  #pragma unroll 8
  for (int i = 0; i < 64; ++i){
    unsigned int u = ctp[(size_t)(b*64 + i)*256 + tid];
    float w = wsh[i];
    union { unsigned int q; float f; } flo, fhi;
    flo.q = u << 16;
    fhi.q = u & 0xffff0000u;
    a0 += w * flo.f;
    a1 += w * fhi.f;
  }
  ((float2*)(ct + b*512))[tid] = make_float2(a0 * invd, a1 * invd);
  if (tid == 0){ mbuf[2*b] = msh[0]; mbuf[2*b + 1] = invd; }
}

// ---- K4: weights[b][s] = exp(score - M_b) * inv_denom
__global__ __launch_bounds__(256) void weights_kernel(const float* __restrict__ scores,
                                                      const float* __restrict__ mbuf,
                                                      float* __restrict__ weights){
  int b = blockIdx.x, tid = threadIdx.x;
  float M = mbuf[2*b], invd = mbuf[2*b + 1];
  const float4* src = (const float4*)(scores + b*4096);
  float4* dst = (float4*)(weights + b*4096);
  #pragma unroll
  for (int i = 0; i < 4; ++i){
    float4 v = src[tid + i*256];
    v.x = __builtin_amdgcn_exp2f((v.x - M) * LOG2E) * invd;
    v.y = __builtin_amdgcn_exp2f((v.y - M) * LOG2E) * invd;
    v.z = __builtin_amdgcn_exp2f((v.z - M) * LOG2E) * invd;
    v.w = __builtin_amdgcn_exp2f((v.w - M) * LOG2E) * invd;
    dst[tid + i*256] = v;
  }
}

// ---- K5: r_t = [c_t,h,x]·Wr^T + br; maxout pairs -> output [32][512]
__global__ __launch_bounds__(256) void final_kernel(
    const float* __restrict__ ct, const float* __restrict__ hvec,
    const float* __restrict__ x, const float* __restrict__ Wr,
    const float* __restrict__ br, float* __restrict__ out){
  __shared__ float xs[8][1536];
  int bt = blockIdx.x >> 4;
  int it = blockIdx.x & 15;
  int tid = threadIdx.x;
  int b0 = bt * 8;
  for (int idx = tid; idx < 8*1536; idx += 256){
    int bl = idx / 1536, j = idx % 1536;
    int b = b0 + bl;
    float v = (j < 512) ? ct[b*512 + j]
            : (j < 1024) ? hvec[b*512 + (j - 512)]
            : x[b*512 + (j - 1024)];
    xs[bl][j] = v;
  }
  __syncthreads();
  int i = it*64 + (tid & 63);
  int bl0 = (tid >> 6) * 2;
  const float4* wrow = (const float4*)(Wr + (size_t)i*1536);
  const float4* x0 = (const float4*)xs[bl0];
  const float4* x1 = (const float4*)xs[bl0 + 1];
  float a0 = 0.f, a1 = 0.f;
  #pragma unroll 4
  for (int k = 0; k < 384; ++k){
    float4 w = wrow[k];
    float4 u0 = x0[k], u1 = x1[k];
    a0 += w.x*u0.x + w.y*u0.y + w.z*u0.z + w.w*u0.w;
    a1 += w.x*u1.x + w.y*u1.y + w.z*u1.z + w.w*u1.w;
  }
  float bias = br[i];
  a0 += bias; a1 += bias;
  float n0 = __shfl_xor(a0, 1);
  float n1 = __shfl_xor(a1, 1);
  if ((tid & 1) == 0){
    out[(b0 + bl0    )*512 + (i >> 1)] = fmaxf(a0, n0);
    out[(b0 + bl0 + 1)*512 + (i >> 1)] = fmaxf(a1, n1);
  }
}

extern "C" void kernel_launch(void* const* d_in, const int* in_sizes, int n_in,
                              void* d_out, int out_size, void* d_ws, size_t ws_size,
                              hipStream_t stream){
  const float* ctx  = (const float*)d_in[0];
  const float* hvec = (const float*)d_in[1];
  const float* x    = (const float*)d_in[2];
  const float* We   = (const float*)d_in[3];
  const float* be   = (const float*)d_in[4];
  const float* Wd   = (const float*)d_in[5];
  const float* bd   = (const float*)d_in[6];
  const float* Wv   = (const float*)d_in[7];
  // d_in[8] = bv: dropped (softmax shift-invariance)
  const float* Wr   = (const float*)d_in[9];
  const float* br   = (const float*)d_in[10];

  float* out     = (float*)d_out;        // output [32][512]
  float* weights = out + 32*512;         // weights [32][4096]

  char* ws = (char*)d_ws;
  unsigned int* weSwz = (unsigned int*)ws;               // 512 KiB
  float* scores  = (float*)(ws + (512 << 10));           // 512 KiB
  unsigned int* ctp = (unsigned int*)(ws + (1024 << 10)); // 2 MiB (2048x256 u32)
  float* MS      = (float*)(ws + (3 << 20));             // 16 KiB
  float* mbuf    = (float*)(ws + (3 << 20) + (24 << 10)); // 256 B
  float* ct      = (float*)(ws + (3 << 20) + (32 << 10)); // 64 KiB
  float* gd      = (float*)(ws + (3 << 20) + (96 << 10)); // 64 KiB region

  we_conv<<<128, 256, 0, stream>>>(We, weSwz);
  gd_kernel<<<128, 256, 0, stream>>>(hvec, Wd, bd, be, gd);
  score_kernel<<<2048, 256, 0, stream>>>(ctx, (const uint4*)weSwz, gd, Wv,
                                         scores, ctp, MS);
  combine_kernel<<<32, 256, 0, stream>>>(ctp, MS, ct, mbuf);
  weights_kernel<<<32, 256, 0, stream>>>(scores, mbuf, weights);
  final_kernel<<<64, 256, 0, stream>>>(ct, hvec, x, Wr, br, out);
}

// Round 16
// 196.569 us; speedup vs baseline: 2.1094x; 2.1094x over previous
//
#include <hip/hip_runtime.h>

// Problem constants: B=32, S=4096, H=512, E=512
typedef __attribute__((ext_vector_type(8))) short bf16x8;
typedef __attribute__((ext_vector_type(16))) float f32x16;

typedef __attribute__((address_space(3))) unsigned int lds_u32;
typedef __attribute__((address_space(1))) unsigned int glb_u32;

__device__ inline unsigned int cvt_pk_bf16(float lo, float hi){
  unsigned int r;
  asm("v_cvt_pk_bf16_f32 %0, %1, %2" : "=v"(r) : "v"(lo), "v"(hi));
  return r;
}
__device__ inline bf16x8 pack8(float4 a, float4 b){
  union { unsigned int u[4]; bf16x8 v; } r;
  r.u[0]=cvt_pk_bf16(a.x,a.y); r.u[1]=cvt_pk_bf16(a.z,a.w);
  r.u[2]=cvt_pk_bf16(b.x,b.y); r.u[3]=cvt_pk_bf16(b.z,b.w);
  return r.v;
}
__device__ inline float fast_tanh(float x){
  float e = __builtin_amdgcn_exp2f(x * 2.8853900817779268f);
  return 1.0f - 2.0f * __builtin_amdgcn_rcpf(e + 1.0f);
}
#define LOG2E 1.4426950408889634f

// ---- K0: We [512][512] f32 -> bf16 fragment images for mfma_32x32x16.
// [round-1 verbatim] weFrag[hc][t][lane] (16B): col=(hc>>1)*32+(lane&31),
// k=(hc&1)*256+t*16+(lane>>5)*8+j. Lane-linear: global_load_lds verbatim +
// conflict-free ds_read_b128.
__global__ __launch_bounds__(256) void we_conv(const float* __restrict__ We,
                                               uint4* __restrict__ weFrag){
  int gid = blockIdx.x * 256 + threadIdx.x;   // 32768 = 32 hc x 16 t x 64 lanes
  int l  = gid & 63;
  int hc = gid >> 10;
  int colv = (hc >> 1)*32 + (l & 31);
  int k = ((hc & 1) << 8) + ((gid >> 6) & 15)*16 + (l >> 5)*8;
  const float4* src = (const float4*)(We + colv*512 + k);
  float4 f0 = src[0], f1 = src[1];
  weFrag[gid] = make_uint4(cvt_pk_bf16(f0.x,f0.y), cvt_pk_bf16(f0.z,f0.w),
                           cvt_pk_bf16(f1.x,f1.y), cvt_pk_bf16(f1.z,f1.w));
}

// ---- K1: gd[b][k] = h[b,:]·Wd[k,:] + bd[k] + be[k]
__global__ __launch_bounds__(256) void gd_kernel(const float* __restrict__ hvec,
                                                 const float* __restrict__ Wd,
                                                 const float* __restrict__ bd,
                                                 const float* __restrict__ be,
                                                 float* __restrict__ gd){
  __shared__ float hs[512];
  int b = blockIdx.x >> 2, kc = blockIdx.x & 3;
  int tid = threadIdx.x;
  hs[tid]       = hvec[b*512 + tid];
  hs[tid + 256] = hvec[b*512 + 256 + tid];
  __syncthreads();
  int k  = kc*128 + (tid >> 1);
  int hh = (tid & 1) * 256;
  const float4* wrow = (const float4*)(Wd + (size_t)k*512 + hh);
  const float4* hv4  = (const float4*)(hs + hh);
  float acc = 0.f;
  #pragma unroll 8
  for (int i = 0; i < 64; ++i){
    float4 w = wrow[i]; float4 u = hv4[i];
    acc += w.x*u.x + w.y*u.y + w.z*u.z + w.w*u.w;
  }
  acc += __shfl_xor(acc, 1);
  if ((tid & 1) == 0) gd[b*512 + k] = acc + bd[k] + be[k];
}

// ---- K2: THE measured-best main loop (round-1 submission, 154us in round-2
// bench) + flash-ct epilogue. 4 waves x 32 rows = 128 rows/block, 1024
// blocks. A-frags global->reg bf16. B staged via global_load_lds into a
// 3x16KB rotation, counted vmcnt(4) waits, 1 barrier per half-chunk.
__global__ __launch_bounds__(256, 2) void score_kernel(
    const float* __restrict__ ctx, const char* __restrict__ weFrag,
    const float* __restrict__ gd, const float* __restrict__ Wv,
    float* __restrict__ scores, unsigned int* __restrict__ ctp,
    float* __restrict__ MS){
  __shared__ char lds[3*16384 + 4096];       // 52 KiB -> 2 blocks/CU
  __shared__ float sc_lds[128];
  __shared__ float w_lds[128];
  __shared__ float red2[2];
  float* gdwv = (float*)(lds + 49152);       // [512 gd][512 Wv]

  const int tid  = threadIdx.x;
  const int wid  = tid >> 6;
  const int lane = tid & 63;
  const int bid  = blockIdx.x;
  const int row0 = bid * 128;
  const int b    = bid >> 5;                 // 32 blocks per batch row
  const int col  = lane & 31;
  const int hi   = lane >> 5;

  // stage gd + Wv into LDS (keeps the k-loop free of compiler VMEM)
  if (tid < 128) ((float4*)gdwv)[tid] = ((const float4*)(gd + b*512))[tid];
  else           ((float4*)gdwv)[tid] = ((const float4*)Wv)[tid - 128];

  // A-fragments: 32 k-steps, register-resident (128 VGPR)
  bf16x8 afrag[32];
  {
    const float4* ap = (const float4*)(ctx + (size_t)(row0 + wid*32 + col)*512 + hi*8);
    #pragma unroll
    for (int t = 0; t < 32; ++t)
      afrag[t] = pack8(ap[t*4], ap[t*4 + 1]);
  }

  asm volatile("s_waitcnt lgkmcnt(0)" ::: "memory");  // gdwv ds_writes done

  #define ISSUE(HC, BUF) do { \
    const char* _g = weFrag + ((size_t)(HC))*16384 + wid*4096; \
    char* _l = lds + (BUF)*16384 + wid*4096; \
    _Pragma("unroll") \
    for (int _i = 0; _i < 4; ++_i) \
      __builtin_amdgcn_global_load_lds((const glb_u32*)(_g + _i*1024 + lane*16), \
                                       (lds_u32*)(_l + _i*1024), 16, 0, 0); \
  } while(0)

  ISSUE(0, 0);
  ISSUE(1, 1);

  f32x16 acc;
  float sc[16];
  #pragma unroll
  for (int r = 0; r < 16; ++r) sc[r] = 0.f;

  for (int nc = 0; nc < 16; ++nc){
    const int hc0 = 2*nc, hc1 = 2*nc + 1;

    // ---- half 0 (k = 0..255)
    asm volatile("s_waitcnt vmcnt(4)" ::: "memory");
    __builtin_amdgcn_s_barrier();             // hc0 landed (all waves); hc0-1 reads done
    if (hc0 < 30) ISSUE(hc0 + 2, (hc0 + 2) % 3);
    {
      const char* bb = lds + (hc0 % 3)*16384 + lane*16;
      #pragma unroll
      for (int r = 0; r < 16; ++r) acc[r] = 0.f;
      __builtin_amdgcn_s_setprio(1);
      #pragma unroll
      for (int t = 0; t < 16; ++t){
        bf16x8 bf = *(const bf16x8*)(bb + t*1024);
        acc = __builtin_amdgcn_mfma_f32_32x32x16_bf16(afrag[t], bf, acc, 0, 0, 0);
      }
      __builtin_amdgcn_s_setprio(0);
    }

    // ---- half 1 (k = 256..511)
    if (nc < 15) asm volatile("s_waitcnt vmcnt(4)" ::: "memory");
    else         asm volatile("s_waitcnt vmcnt(0)" ::: "memory");
    __builtin_amdgcn_s_barrier();
    if (hc1 < 30) ISSUE(hc1 + 2, (hc1 + 2) % 3);
    {
      const char* bb = lds + (hc1 % 3)*16384 + lane*16;
      __builtin_amdgcn_s_setprio(1);
      #pragma unroll
      for (int t = 0; t < 16; ++t){
        bf16x8 bf = *(const bf16x8*)(bb + t*1024);
        acc = __builtin_amdgcn_mfma_f32_32x32x16_bf16(afrag[16 + t], bf, acc, 0, 0, 0);
      }
      __builtin_amdgcn_s_setprio(0);
    }

    // ---- epilogue: sc[r] += tanh(acc + gd) * Wv   (col = nc*32 + lane&31)
    {
      float gdv = gdwv[nc*32 + col];
      float wvv = gdwv[512 + nc*32 + col];
      #pragma unroll
      for (int r = 0; r < 16; ++r)
        sc[r] += fast_tanh(acc[r] + gdv) * wvv;
    }
  }
  #undef ISSUE

  // reduce over the 32 columns (lanes 0-31 / 32-63 hold distinct rows)
  #pragma unroll
  for (int r = 0; r < 16; ++r){
    #pragma unroll
    for (int m = 1; m <= 16; m <<= 1) sc[r] += __shfl_xor(sc[r], m);
  }
  if (col == 0){
    int rbase = wid*32 + 4*hi;
    float* so = scores + row0 + rbase;
    #pragma unroll
    for (int r = 0; r < 16; ++r){
      int rr = (r & 3) + 8*(r >> 2);
      so[rr] = sc[r];                         // global (for weights kernel)
      sc_lds[rbase + rr] = sc[r];             // block-local
    }
  }
  __syncthreads();                            // sc_lds ready; lds reads done

  // ---- block-local softmax partials over 128 rows
  float M = -1e30f;
  {
    const float4* s4 = (const float4*)sc_lds;
    #pragma unroll
    for (int i = 0; i < 32; ++i){
      float4 v = s4[i];
      M = fmaxf(M, fmaxf(fmaxf(v.x, v.y), fmaxf(v.z, v.w)));
    }
  }
  if (tid < 128){
    float w = __builtin_amdgcn_exp2f((sc_lds[tid] - M) * LOG2E);
    w_lds[tid] = w;
    #pragma unroll
    for (int o = 1; o < 64; o <<= 1) w += __shfl_xor(w, o);
    if ((tid & 63) == 0) red2[tid >> 6] = w;
  }
  __syncthreads();
  float S_blk = red2[0] + red2[1];

  // ---- ctp[h] = sum_r w_r * A[r,h]; 4 passes of 32 rows via lds[0,32K)
  float cA = 0.f, cB = 0.f;                   // h = 2*tid, 2*tid+1
  #pragma unroll
  for (int p = 0; p < 4; ++p){
    if (wid == p){                            // wave p dumps its 32 rows
      int rl = col;                           // row within pass 0..31
      char* dst = lds + rl*1024;
      int swz = (rl & 7) << 4;
      #pragma unroll
      for (int t = 0; t < 32; ++t){
        union { bf16x8 v; uint4 q; } u; u.v = afrag[t];
        *(uint4*)(dst + ((t*32 + hi*16) ^ swz)) = u.q;
      }
    }
    __syncthreads();
    const float* wp = w_lds + p*32;
    #pragma unroll 8
    for (int r = 0; r < 32; ++r){
      unsigned int u = *(const unsigned int*)(lds + r*1024 + ((tid*4) ^ ((r & 7) << 4)));
      float cw = wp[r];
      union { unsigned int q; float f; } flo, fhi;
      flo.q = u << 16;
      fhi.q = u & 0xffff0000u;
      cA += cw * flo.f;
      cB += cw * fhi.f;
    }
    __syncthreads();
  }
  ctp[(size_t)bid*256 + tid] = cvt_pk_bf16(cA, cB);
  if (tid == 0){ MS[2*bid] = M; MS[2*bid + 1] = S_blk; }
}

// ---- K3: combine 32 slab-partials per batch -> ct[b][512], mbuf[b]={M,1/den}
__global__ __launch_bounds__(256) void combine_kernel(const unsigned int* __restrict__ ctp,
                                                      const float* __restrict__ MS,
                                                      float* __restrict__ ct,
                                                      float* __restrict__ mbuf){
  __shared__ float wsh[32];
  __shared__ float msh[2];
  int b = blockIdx.x, tid = threadIdx.x;
  if (tid < 32){
    float Mi = MS[(b*32 + tid)*2];
    float Si = MS[(b*32 + tid)*2 + 1];
    float M = Mi;
    #pragma unroll
    for (int o = 1; o < 32; o <<= 1) M = fmaxf(M, __shfl_xor(M, o));
    float w = __builtin_amdgcn_exp2f((Mi - M) * LOG2E);
    float d = w * Si;
    #pragma unroll
    for (int o = 1; o < 32; o <<= 1) d += __shfl_xor(d, o);
    wsh[tid] = w;
    if (tid == 0){ msh[0] = M; msh[1] = 1.0f / d; }
  }
  __syncthreads();
  float invd = msh[1];
  float a0 = 0.f, a1 = 0.f;
  #pragma unroll 8
  for (int i = 0; i < 32; ++i){
    unsigned int u = ctp[(size_t)(b*32 + i)*256 + tid];
    float w = wsh[i];
    union { unsigned int q; float f; } flo, fhi;
    flo.q = u << 16;
    fhi.q = u & 0xffff0000u;
    a0 += w * flo.f;
    a1 += w * fhi.f;
  }
  ((float2*)(ct + b*512))[tid] = make_float2(a0 * invd, a1 * invd);
  if (tid == 0){ mbuf[2*b] = msh[0]; mbuf[2*b + 1] = invd; }
}

// ---- K4: weights[b][s] = exp(score - M_b) * inv_denom
__global__ __launch_bounds__(256) void weights_kernel(const float* __restrict__ scores,
                                                      const float* __restrict__ mbuf,
                                                      float* __restrict__ weights){
  int b = blockIdx.x, tid = threadIdx.x;
  float M = mbuf[2*b], invd = mbuf[2*b + 1];
  const float4* src = (const float4*)(scores + b*4096);
  float4* dst = (float4*)(weights + b*4096);
  #pragma unroll
  for (int i = 0; i < 4; ++i){
    float4 v = src[tid + i*256];
    v.x = __builtin_amdgcn_exp2f((v.x - M) * LOG2E) * invd;
    v.y = __builtin_amdgcn_exp2f((v.y - M) * LOG2E) * invd;
    v.z = __builtin_amdgcn_exp2f((v.z - M) * LOG2E) * invd;
    v.w = __builtin_amdgcn_exp2f((v.w - M) * LOG2E) * invd;
    dst[tid + i*256] = v;
  }
}

// ---- K5: r_t = [c_t,h,x]·Wr^T + br; maxout pairs -> output [32][512]
__global__ __launch_bounds__(256) void final_kernel(
    const float* __restrict__ ct, const float* __restrict__ hvec,
    const float* __restrict__ x, const float* __restrict__ Wr,
    const float* __restrict__ br, float* __restrict__ out){
  __shared__ float xs[8][1536];
  int bt = blockIdx.x >> 4;
  int it = blockIdx.x & 15;
  int tid = threadIdx.x;
  int b0 = bt * 8;
  for (int idx = tid; idx < 8*1536; idx += 256){
    int bl = idx / 1536, j = idx % 1536;
    int b = b0 + bl;
    float v = (j < 512) ? ct[b*512 + j]
            : (j < 1024) ? hvec[b*512 + (j - 512)]
            : x[b*512 + (j - 1024)];
    xs[bl][j] = v;
  }
  __syncthreads();
  int i = it*64 + (tid & 63);
  int bl0 = (tid >> 6) * 2;
  const float4* wrow = (const float4*)(Wr + (size_t)i*1536);
  const float4* x0 = (const float4*)xs[bl0];
  const float4* x1 = (const float4*)xs[bl0 + 1];
  float a0 = 0.f, a1 = 0.f;
  #pragma unroll 4
  for (int k = 0; k < 384; ++k){
    float4 w = wrow[k];
    float4 u0 = x0[k], u1 = x1[k];
    a0 += w.x*u0.x + w.y*u0.y + w.z*u0.z + w.w*u0.w;
    a1 += w.x*u1.x + w.y*u1.y + w.z*u1.z + w.w*u1.w;
  }
  float bias = br[i];
  a0 += bias; a1 += bias;
  float n0 = __shfl_xor(a0, 1);
  float n1 = __shfl_xor(a1, 1);
  if ((tid & 1) == 0){
    out[(b0 + bl0    )*512 + (i >> 1)] = fmaxf(a0, n0);
    out[(b0 + bl0 + 1)*512 + (i >> 1)] = fmaxf(a1, n1);
  }
}

extern "C" void kernel_launch(void* const* d_in, const int* in_sizes, int n_in,
                              void* d_out, int out_size, void* d_ws, size_t ws_size,
                              hipStream_t stream){
  const float* ctx  = (const float*)d_in[0];
  const float* hvec = (const float*)d_in[1];
  const float* x    = (const float*)d_in[2];
  const float* We   = (const float*)d_in[3];
  const float* be   = (const float*)d_in[4];
  const float* Wd   = (const float*)d_in[5];
  const float* bd   = (const float*)d_in[6];
  const float* Wv   = (const float*)d_in[7];
  // d_in[8] = bv: dropped (softmax shift-invariance)
  const float* Wr   = (const float*)d_in[9];
  const float* br   = (const float*)d_in[10];

  float* out     = (float*)d_out;        // output [32][512]
  float* weights = out + 32*512;         // weights [32][4096]

  char* ws = (char*)d_ws;
  char* weFrag   = ws;                                    // 512 KiB
  float* scores  = (float*)(ws + (512 << 10));            // 512 KiB
  unsigned int* ctp = (unsigned int*)(ws + (1024 << 10)); // 1 MiB (1024x256 u32)
  float* MS      = (float*)(ws + (2 << 20));              // 8 KiB
  float* mbuf    = (float*)(ws + (2 << 20) + (16 << 10)); // 256 B
  float* ct      = (float*)(ws + (2 << 20) + (32 << 10)); // 64 KiB
  float* gd      = (float*)(ws + (2 << 20) + (96 << 10)); // 64 KiB region

  we_conv<<<128, 256, 0, stream>>>(We, (uint4*)weFrag);
  gd_kernel<<<128, 256, 0, stream>>>(hvec, Wd, bd, be, gd);
  score_kernel<<<1024, 256, 0, stream>>>(ctx, weFrag, gd, Wv, scores, ctp, MS);
  combine_kernel<<<32, 256, 0, stream>>>(ctp, MS, ct, mbuf);
  weights_kernel<<<32, 256, 0, stream>>>(scores, mbuf, weights);
  final_kernel<<<64, 256, 0, stream>>>(ct, hvec, x, Wr, br, out);
}

// Round 17
// 190.556 us; speedup vs baseline: 2.1760x; 1.0316x over previous
//
#include <hip/hip_runtime.h>

// Problem constants: B=32, S=4096, H=512, E=512
typedef __attribute__((ext_vector_type(8))) short bf16x8;
typedef __attribute__((ext_vector_type(16))) float f32x16;

typedef __attribute__((address_space(3))) unsigned int lds_u32;
typedef __attribute__((address_space(1))) unsigned int glb_u32;

__device__ inline unsigned int cvt_pk_bf16(float lo, float hi){
  unsigned int r;
  asm("v_cvt_pk_bf16_f32 %0, %1, %2" : "=v"(r) : "v"(lo), "v"(hi));
  return r;
}
__device__ inline bf16x8 pack8(float4 a, float4 b){
  union { unsigned int u[4]; bf16x8 v; } r;
  r.u[0]=cvt_pk_bf16(a.x,a.y); r.u[1]=cvt_pk_bf16(a.z,a.w);
  r.u[2]=cvt_pk_bf16(b.x,b.y); r.u[3]=cvt_pk_bf16(b.z,b.w);
  return r.v;
}
__device__ inline float fast_tanh(float x){
  float e = __builtin_amdgcn_exp2f(x * 2.8853900817779268f);
  return 1.0f - 2.0f * __builtin_amdgcn_rcpf(e + 1.0f);
}
#define LOG2E 1.4426950408889634f

// ---- K0: We [512][512] f32 -> bf16 fragment images for mfma_32x32x16.
// [round-1 verbatim] weFrag[hc][t][lane] (16B): col=(hc>>1)*32+(lane&31),
// k=(hc&1)*256+t*16+(lane>>5)*8+j.
__global__ __launch_bounds__(256) void we_conv(const float* __restrict__ We,
                                               uint4* __restrict__ weFrag){
  int gid = blockIdx.x * 256 + threadIdx.x;   // 32768 = 32 hc x 16 t x 64 lanes
  int l  = gid & 63;
  int hc = gid >> 10;
  int colv = (hc >> 1)*32 + (l & 31);
  int k = ((hc & 1) << 8) + ((gid >> 6) & 15)*16 + (l >> 5)*8;
  const float4* src = (const float4*)(We + colv*512 + k);
  float4 f0 = src[0], f1 = src[1];
  weFrag[gid] = make_uint4(cvt_pk_bf16(f0.x,f0.y), cvt_pk_bf16(f0.z,f0.w),
                           cvt_pk_bf16(f1.x,f1.y), cvt_pk_bf16(f1.z,f1.w));
}

// ---- K1: gd[b][k] = h[b,:]·Wd[k,:] + bd[k] + be[k]
__global__ __launch_bounds__(256) void gd_kernel(const float* __restrict__ hvec,
                                                 const float* __restrict__ Wd,
                                                 const float* __restrict__ bd,
                                                 const float* __restrict__ be,
                                                 float* __restrict__ gd){
  __shared__ float hs[512];
  int b = blockIdx.x >> 2, kc = blockIdx.x & 3;
  int tid = threadIdx.x;
  hs[tid]       = hvec[b*512 + tid];
  hs[tid + 256] = hvec[b*512 + 256 + tid];
  __syncthreads();
  int k  = kc*128 + (tid >> 1);
  int hh = (tid & 1) * 256;
  const float4* wrow = (const float4*)(Wd + (size_t)k*512 + hh);
  const float4* hv4  = (const float4*)(hs + hh);
  float acc = 0.f;
  #pragma unroll 8
  for (int i = 0; i < 64; ++i){
    float4 w = wrow[i]; float4 u = hv4[i];
    acc += w.x*u.x + w.y*u.y + w.z*u.z + w.w*u.w;
  }
  acc += __shfl_xor(acc, 1);
  if ((tid & 1) == 0) gd[b*512 + k] = acc + bd[k] + be[k];
}

// ---- K2: r1 main loop + flash-ct epilogue, with epilogue scratch ALIASED
// into the gdwv region so LDS stays at exactly 53248 B -> 3 blocks/CU
// (the 54784B r16 variant fell over the 160KiB/3 = 54613B cliff).
__global__ __launch_bounds__(256, 2) void score_kernel(
    const float* __restrict__ ctx, const char* __restrict__ weFrag,
    const float* __restrict__ gd, const float* __restrict__ Wv,
    float* __restrict__ scores, unsigned int* __restrict__ ctp,
    float* __restrict__ MS){
  __shared__ char lds[3*16384 + 4096];       // 52 KiB exactly -> 3 blocks/CU
  float* gdwv = (float*)(lds + 49152);       // [512 gd][512 Wv]; reused post-loop

  const int tid  = threadIdx.x;
  const int wid  = tid >> 6;
  const int lane = tid & 63;
  const int bid  = blockIdx.x;
  const int row0 = bid * 128;
  const int b    = bid >> 5;                 // 32 blocks per batch row
  const int col  = lane & 31;
  const int hi   = lane >> 5;

  // stage gd + Wv into LDS (keeps the k-loop free of compiler VMEM)
  if (tid < 128) ((float4*)gdwv)[tid] = ((const float4*)(gd + b*512))[tid];
  else           ((float4*)gdwv)[tid] = ((const float4*)Wv)[tid - 128];

  // A-fragments: 32 k-steps, register-resident (128 VGPR)
  bf16x8 afrag[32];
  {
    const float4* ap = (const float4*)(ctx + (size_t)(row0 + wid*32 + col)*512 + hi*8);
    #pragma unroll
    for (int t = 0; t < 32; ++t)
      afrag[t] = pack8(ap[t*4], ap[t*4 + 1]);
  }

  asm volatile("s_waitcnt lgkmcnt(0)" ::: "memory");  // gdwv ds_writes done

  #define ISSUE(HC, BUF) do { \
    const char* _g = weFrag + ((size_t)(HC))*16384 + wid*4096; \
    char* _l = lds + (BUF)*16384 + wid*4096; \
    _Pragma("unroll") \
    for (int _i = 0; _i < 4; ++_i) \
      __builtin_amdgcn_global_load_lds((const glb_u32*)(_g + _i*1024 + lane*16), \
                                       (lds_u32*)(_l + _i*1024), 16, 0, 0); \
  } while(0)

  ISSUE(0, 0);
  ISSUE(1, 1);

  f32x16 acc;
  float sc[16];
  #pragma unroll
  for (int r = 0; r < 16; ++r) sc[r] = 0.f;

  for (int nc = 0; nc < 16; ++nc){
    const int hc0 = 2*nc, hc1 = 2*nc + 1;

    // ---- half 0 (k = 0..255)
    asm volatile("s_waitcnt vmcnt(4)" ::: "memory");
    __builtin_amdgcn_s_barrier();             // hc0 landed; hc0-1 reads done
    if (hc0 < 30) ISSUE(hc0 + 2, (hc0 + 2) % 3);
    {
      const char* bb = lds + (hc0 % 3)*16384 + lane*16;
      #pragma unroll
      for (int r = 0; r < 16; ++r) acc[r] = 0.f;
      __builtin_amdgcn_s_setprio(1);
      #pragma unroll
      for (int t = 0; t < 16; ++t){
        bf16x8 bf = *(const bf16x8*)(bb + t*1024);
        acc = __builtin_amdgcn_mfma_f32_32x32x16_bf16(afrag[t], bf, acc, 0, 0, 0);
      }
      __builtin_amdgcn_s_setprio(0);
    }

    // ---- half 1 (k = 256..511)
    if (nc < 15) asm volatile("s_waitcnt vmcnt(4)" ::: "memory");
    else         asm volatile("s_waitcnt vmcnt(0)" ::: "memory");
    __builtin_amdgcn_s_barrier();
    if (hc1 < 30) ISSUE(hc1 + 2, (hc1 + 2) % 3);
    {
      const char* bb = lds + (hc1 % 3)*16384 + lane*16;
      __builtin_amdgcn_s_setprio(1);
      #pragma unroll
      for (int t = 0; t < 16; ++t){
        bf16x8 bf = *(const bf16x8*)(bb + t*1024);
        acc = __builtin_amdgcn_mfma_f32_32x32x16_bf16(afrag[16 + t], bf, acc, 0, 0, 0);
      }
      __builtin_amdgcn_s_setprio(0);
    }

    // ---- epilogue: sc[r] += tanh(acc + gd) * Wv   (col = nc*32 + lane&31)
    {
      float gdv = gdwv[nc*32 + col];
      float wvv = gdwv[512 + nc*32 + col];
      #pragma unroll
      for (int r = 0; r < 16; ++r)
        sc[r] += fast_tanh(acc[r] + gdv) * wvv;
    }
  }
  #undef ISSUE

  // reduce over the 32 columns (lanes 0-31 / 32-63 hold distinct rows)
  #pragma unroll
  for (int r = 0; r < 16; ++r){
    #pragma unroll
    for (int m = 1; m <= 16; m <<= 1) sc[r] += __shfl_xor(sc[r], m);
  }

  // ---- epilogue scratch ALIASES gdwv region (dead after the k-loop)
  float* scl  = gdwv;                        // [128] block scores
  float* wl   = gdwv + 128;                  // [128] exp weights
  float* redp = gdwv + 256;                  // [2]   partial sums
  __syncthreads();                           // all waves done reading gdwv

  if (col == 0){
    int rbase = wid*32 + 4*hi;
    float* so = scores + row0 + rbase;
    #pragma unroll
    for (int r = 0; r < 16; ++r){
      int rr = (r & 3) + 8*(r >> 2);
      so[rr] = sc[r];                         // global (for weights kernel)
      scl[rbase + rr] = sc[r];                // block-local
    }
  }
  __syncthreads();                            // scl ready; lds buffers free

  // ---- block-local softmax partials over 128 rows
  float M = -1e30f;
  {
    const float4* s4 = (const float4*)scl;
    #pragma unroll
    for (int i = 0; i < 32; ++i){
      float4 v = s4[i];
      M = fmaxf(M, fmaxf(fmaxf(v.x, v.y), fmaxf(v.z, v.w)));
    }
  }
  if (tid < 128){
    float w = __builtin_amdgcn_exp2f((scl[tid] - M) * LOG2E);
    wl[tid] = w;
    #pragma unroll
    for (int o = 1; o < 64; o <<= 1) w += __shfl_xor(w, o);
    if ((tid & 63) == 0) redp[tid >> 6] = w;
  }
  __syncthreads();
  float S_blk = redp[0] + redp[1];

  // ---- ctp[h] = sum_r w_r * A[r,h]; 4 passes of 32 rows via lds[0,32K)
  float cA = 0.f, cB = 0.f;                   // h = 2*tid, 2*tid+1
  #pragma unroll
  for (int p = 0; p < 4; ++p){
    if (wid == p){                            // wave p dumps its 32 rows
      int rl = col;                           // row within pass 0..31
      char* dst = lds + rl*1024;
      int swz = (rl & 7) << 4;
      #pragma unroll
      for (int t = 0; t < 32; ++t){
        union { bf16x8 v; uint4 q; } u; u.v = afrag[t];
        *(uint4*)(dst + ((t*32 + hi*16) ^ swz)) = u.q;
      }
    }
    __syncthreads();
    const float* wp = wl + p*32;
    #pragma unroll 8
    for (int r = 0; r < 32; ++r){
      unsigned int u = *(const unsigned int*)(lds + r*1024 + ((tid*4) ^ ((r & 7) << 4)));
      float cw = wp[r];
      union { unsigned int q; float f; } flo, fhi;
      flo.q = u << 16;
      fhi.q = u & 0xffff0000u;
      cA += cw * flo.f;
      cB += cw * fhi.f;
    }
    __syncthreads();
  }
  ctp[(size_t)bid*256 + tid] = cvt_pk_bf16(cA, cB);
  if (tid == 0){ MS[2*bid] = M; MS[2*bid + 1] = S_blk; }
}

// ---- K3: combine 32 slab-partials per batch -> ct[b][512], mbuf[b]={M,1/den}
__global__ __launch_bounds__(256) void combine_kernel(const unsigned int* __restrict__ ctp,
                                                      const float* __restrict__ MS,
                                                      float* __restrict__ ct,
                                                      float* __restrict__ mbuf){
  __shared__ float wsh[32];
  __shared__ float msh[2];
  int b = blockIdx.x, tid = threadIdx.x;
  if (tid < 32){
    float Mi = MS[(b*32 + tid)*2];
    float Si = MS[(b*32 + tid)*2 + 1];
    float M = Mi;
    #pragma unroll
    for (int o = 1; o < 32; o <<= 1) M = fmaxf(M, __shfl_xor(M, o));
    float w = __builtin_amdgcn_exp2f((Mi - M) * LOG2E);
    float d = w * Si;
    #pragma unroll
    for (int o = 1; o < 32; o <<= 1) d += __shfl_xor(d, o);
    wsh[tid] = w;
    if (tid == 0){ msh[0] = M; msh[1] = 1.0f / d; }
  }
  __syncthreads();
  float invd = msh[1];
  float a0 = 0.f, a1 = 0.f;
  #pragma unroll 8
  for (int i = 0; i < 32; ++i){
    unsigned int u = ctp[(size_t)(b*32 + i)*256 + tid];
    float w = wsh[i];
    union { unsigned int q; float f; } flo, fhi;
    flo.q = u << 16;
    fhi.q = u & 0xffff0000u;
    a0 += w * flo.f;
    a1 += w * fhi.f;
  }
  ((float2*)(ct + b*512))[tid] = make_float2(a0 * invd, a1 * invd);
  if (tid == 0){ mbuf[2*b] = msh[0]; mbuf[2*b + 1] = invd; }
}

// ---- K4: weights[b][s] = exp(score - M_b) * inv_denom
__global__ __launch_bounds__(256) void weights_kernel(const float* __restrict__ scores,
                                                      const float* __restrict__ mbuf,
                                                      float* __restrict__ weights){
  int b = blockIdx.x, tid = threadIdx.x;
  float M = mbuf[2*b], invd = mbuf[2*b + 1];
  const float4* src = (const float4*)(scores + b*4096);
  float4* dst = (float4*)(weights + b*4096);
  #pragma unroll
  for (int i = 0; i < 4; ++i){
    float4 v = src[tid + i*256];
    v.x = __builtin_amdgcn_exp2f((v.x - M) * LOG2E) * invd;
    v.y = __builtin_amdgcn_exp2f((v.y - M) * LOG2E) * invd;
    v.z = __builtin_amdgcn_exp2f((v.z - M) * LOG2E) * invd;
    v.w = __builtin_amdgcn_exp2f((v.w - M) * LOG2E) * invd;
    dst[tid + i*256] = v;
  }
}

// ---- K5: r_t = [c_t,h,x]·Wr^T + br; maxout pairs -> output [32][512]
__global__ __launch_bounds__(256) void final_kernel(
    const float* __restrict__ ct, const float* __restrict__ hvec,
    const float* __restrict__ x, const float* __restrict__ Wr,
    const float* __restrict__ br, float* __restrict__ out){
  __shared__ float xs[8][1536];
  int bt = blockIdx.x >> 4;
  int it = blockIdx.x & 15;
  int tid = threadIdx.x;
  int b0 = bt * 8;
  for (int idx = tid; idx < 8*1536; idx += 256){
    int bl = idx / 1536, j = idx % 1536;
    int b = b0 + bl;
    float v = (j < 512) ? ct[b*512 + j]
            : (j < 1024) ? hvec[b*512 + (j - 512)]
            : x[b*512 + (j - 1024)];
    xs[bl][j] = v;
  }
  __syncthreads();
  int i = it*64 + (tid & 63);
  int bl0 = (tid >> 6) * 2;
  const float4* wrow = (const float4*)(Wr + (size_t)i*1536);
  const float4* x0 = (const float4*)xs[bl0];
  const float4* x1 = (const float4*)xs[bl0 + 1];
  float a0 = 0.f, a1 = 0.f;
  #pragma unroll 4
  for (int k = 0; k < 384; ++k){
    float4 w = wrow[k];
    float4 u0 = x0[k], u1 = x1[k];
    a0 += w.x*u0.x + w.y*u0.y + w.z*u0.z + w.w*u0.w;
    a1 += w.x*u1.x + w.y*u1.y + w.z*u1.z + w.w*u1.w;
  }
  float bias = br[i];
  a0 += bias; a1 += bias;
  float n0 = __shfl_xor(a0, 1);
  float n1 = __shfl_xor(a1, 1);
  if ((tid & 1) == 0){
    out[(b0 + bl0    )*512 + (i >> 1)] = fmaxf(a0, n0);
    out[(b0 + bl0 + 1)*512 + (i >> 1)] = fmaxf(a1, n1);
  }
}

extern "C" void kernel_launch(void* const* d_in, const int* in_sizes, int n_in,
                              void* d_out, int out_size, void* d_ws, size_t ws_size,
                              hipStream_t stream){
  const float* ctx  = (const float*)d_in[0];
  const float* hvec = (const float*)d_in[1];
  const float* x    = (const float*)d_in[2];
  const float* We   = (const float*)d_in[3];
  const float* be   = (const float*)d_in[4];
  const float* Wd   = (const float*)d_in[5];
  const float* bd   = (const float*)d_in[6];
  const float* Wv   = (const float*)d_in[7];
  // d_in[8] = bv: dropped (softmax shift-invariance)
  const float* Wr   = (const float*)d_in[9];
  const float* br   = (const float*)d_in[10];

  float* out     = (float*)d_out;        // output [32][512]
  float* weights = out + 32*512;         // weights [32][4096]

  char* ws = (char*)d_ws;
  char* weFrag   = ws;                                    // 512 KiB
  float* scores  = (float*)(ws + (512 << 10));            // 512 KiB
  unsigned int* ctp = (unsigned int*)(ws + (1024 << 10)); // 1 MiB (1024x256 u32)
  float* MS      = (float*)(ws + (2 << 20));              // 8 KiB
  float* mbuf    = (float*)(ws + (2 << 20) + (16 << 10)); // 256 B
  float* ct      = (float*)(ws + (2 << 20) + (32 << 10)); // 64 KiB
  float* gd      = (float*)(ws + (2 << 20) + (96 << 10)); // 64 KiB region

  we_conv<<<128, 256, 0, stream>>>(We, (uint4*)weFrag);
  gd_kernel<<<128, 256, 0, stream>>>(hvec, Wd, bd, be, gd);
  score_kernel<<<1024, 256, 0, stream>>>(ctx, weFrag, gd, Wv, scores, ctp, MS);
  combine_kernel<<<32, 256, 0, stream>>>(ctp, MS, ct, mbuf);
  weights_kernel<<<32, 256, 0, stream>>>(scores, mbuf, weights);
  final_kernel<<<64, 256, 0, stream>>>(ct, hvec, x, Wr, br, out);
}